// Round 16
// baseline (1005.975 us; speedup 1.0000x reference)
//
#include <hip/hip_runtime.h>

typedef float v2f __attribute__((ext_vector_type(2)));
typedef float v4f __attribute__((ext_vector_type(4)));

#define BATCH 2048
#define TSEQ 512
#define FUT 64
#define TOUT (TSEQ + FUT)   // 576
#define HID 50
#define RPW 2               // rows per wave (weights amortized over both)
#define WPB 4               // waves per block
#define RPB (RPW * WPB)     // 8 rows per block -> 256 blocks, 1024 waves total
                            // = exactly 1 wave/SIMD on 256 CUs (one pass)

// R15: __launch_bounds__(256,1) -> 512-reg unified budget per wave, so the
// 200-float per-lane weight set can live in arch VGPRs (<=256 addressable)
// instead of being demoted to AGPR/scratch (the ~290 instr/step tax measured
// in R5/R11/R14). Two rows per wave: the register-resident weights feed two
// independent recurrence chains (ILP covers the 1-wave/SIMD latency).
// Rank-1 fold (R14, verified) retained: future phase needs no feedback.

__device__ __forceinline__ float rcp_f(float x) { return __builtin_amdgcn_rcpf(x); }
__device__ __forceinline__ float sigm(float x)  { return rcp_f(1.f + __expf(-x)); }
__device__ __forceinline__ float tanh_f(float x){ return 1.f - 2.f * rcp_f(__expf(2.f * x) + 1.f); }

__device__ __forceinline__ void pkfma(v2f& acc, v2f a, v2f b) {
  asm("v_pk_fma_f32 %0, %1, %2, %0" : "+v"(acc) : "v"(a), "v"(b));
}

__global__ __launch_bounds__(256, 1) void lstm_seq_kernel(
    const float* __restrict__ x,      // [B, T]
    const float* __restrict__ W_ih,   // [200, 1]
    const float* __restrict__ W_hh,   // [200, 50]
    const float* __restrict__ b_ih,   // [200]
    const float* __restrict__ b_hh,   // [200]
    const float* __restrict__ W_out,  // [1, 50]
    const float* __restrict__ b_out,  // [1]
    float* __restrict__ out)          // [B, 576]
{
  __shared__ float sx[RPB][TSEQ];   // 16 KB: input rows for this block
  __shared__ float sH[RPB][64];     // 2 KB: per-row h broadcast (wave-private)

  const int tid  = threadIdx.x;
  const int wv   = tid >> 6;
  const int lane = tid & 63;
  const int r0   = blockIdx.x * RPB + 2 * wv;      // this wave's two rows

  for (int i = tid; i < RPB * TSEQ; i += 256)
    ((float*)sx)[i] = x[(size_t)blockIdx.x * RPB * TSEQ + i];
  for (int i = tid; i < RPB * 64; i += 256) ((float*)sH)[i] = 0.f;
  __syncthreads();                  // the ONLY barrier

  const bool act = (lane < HID);
  const int  kk  = act ? lane : 0;

  // per-lane weights: rows {kk, kk+50, kk+100, kk+150} of W_hh (one-time load)
  v2f wi[25], wf[25], wg[25], wo[25];
  {
    const v2f* q0 = (const v2f*)(W_hh + (0 * HID + kk) * HID);
    const v2f* q1 = (const v2f*)(W_hh + (1 * HID + kk) * HID);
    const v2f* q2 = (const v2f*)(W_hh + (2 * HID + kk) * HID);
    const v2f* q3 = (const v2f*)(W_hh + (3 * HID + kk) * HID);
    #pragma unroll
    for (int j = 0; j < 25; ++j) { wi[j] = q0[j]; wf[j] = q1[j]; wg[j] = q2[j]; wo[j] = q3[j]; }
  }
  float bi = b_ih[0 * HID + kk] + b_hh[0 * HID + kk];
  float bf = b_ih[1 * HID + kk] + b_hh[1 * HID + kk];
  float bg = b_ih[2 * HID + kk] + b_hh[2 * HID + kk];
  float bo = b_ih[3 * HID + kk] + b_hh[3 * HID + kk];
  const float wxi = W_ih[0 * HID + kk];
  const float wxf = W_ih[1 * HID + kk];
  const float wxg = W_ih[2 * HID + kk];
  const float wxo = W_ih[3 * HID + kk];
  const float wout = act ? W_out[kk] : 0.f;
  const float bout = b_out[0];

  float h0 = 0.f, c0 = 0.f, h1 = 0.f, c1 = 0.f;
  float* orow0 = out + (size_t)r0 * TOUT;
  float* orow1 = orow0 + TOUT;
  const v4f* sH4a = (const v4f*)sH[2 * wv];
  const v4f* sH4b = (const v4f*)sH[2 * wv + 1];
  const v2f* sH2a = (const v2f*)sH[2 * wv];
  const v2f* sH2b = (const v2f*)sH[2 * wv + 1];

  #pragma unroll 1
  for (int t = 0; t < TOUT; ++t) {
    if (t == TSEQ) {
      // one-time rank-1 fold: W += W_ih (x) W_out ; b += W_ih * b_out.
      // out_t is linear in h_t, so the autoregressive input term is exact.
      const v2f* wo2 = (const v2f*)W_out;
      const v2f xi = {wxi, wxi}, xf = {wxf, wxf}, xg = {wxg, wxg}, xo = {wxo, wxo};
      #pragma unroll
      for (int j = 0; j < 25; ++j) {
        const v2f wv_ = wo2[j];
        pkfma(wi[j], xi, wv_);
        pkfma(wf[j], xf, wv_);
        pkfma(wg[j], xg, wv_);
        pkfma(wo[j], xo, wv_);
      }
      bi = fmaf(wxi, bout, bi);
      bf = fmaf(wxf, bout, bf);
      bg = fmaf(wxg, bout, bg);
      bo = fmaf(wxo, bout, bo);
    }
    const float xv0 = (t < TSEQ) ? sx[2 * wv][t] : 0.f;
    const float xv1 = (t < TSEQ) ? sx[2 * wv + 1][t] : 0.f;

    sH[2 * wv][lane] = h0;            // wave-private; waitcnt-ordered vs reads
    sH[2 * wv + 1][lane] = h1;

    v2f ai0 = {fmaf(xv0, wxi, bi), 0.f}, ai1 = {fmaf(xv1, wxi, bi), 0.f};
    v2f af0 = {fmaf(xv0, wxf, bf), 0.f}, af1 = {fmaf(xv1, wxf, bf), 0.f};
    v2f ag0 = {fmaf(xv0, wxg, bg), 0.f}, ag1 = {fmaf(xv1, wxg, bg), 0.f};
    v2f ao0 = {fmaf(xv0, wxo, bo), 0.f}, ao1 = {fmaf(xv1, wxo, bo), 0.f};
    #pragma unroll
    for (int q = 0; q < 12; ++q) {    // m = 0..47: uniform b128 broadcast reads
      const v4f ha4 = sH4a[q];
      const v4f hb4 = sH4b[q];
      const v2f haA = {ha4.x, ha4.y}, haB = {ha4.z, ha4.w};
      const v2f hbA = {hb4.x, hb4.y}, hbB = {hb4.z, hb4.w};
      pkfma(ai0, wi[2 * q], haA); pkfma(ai0, wi[2 * q + 1], haB);
      pkfma(ai1, wi[2 * q], hbA); pkfma(ai1, wi[2 * q + 1], hbB);
      pkfma(af0, wf[2 * q], haA); pkfma(af0, wf[2 * q + 1], haB);
      pkfma(af1, wf[2 * q], hbA); pkfma(af1, wf[2 * q + 1], hbB);
      pkfma(ag0, wg[2 * q], haA); pkfma(ag0, wg[2 * q + 1], haB);
      pkfma(ag1, wg[2 * q], hbA); pkfma(ag1, wg[2 * q + 1], hbB);
      pkfma(ao0, wo[2 * q], haA); pkfma(ao0, wo[2 * q + 1], haB);
      pkfma(ao1, wo[2 * q], hbA); pkfma(ao1, wo[2 * q + 1], hbB);
    }
    { const v2f hta = sH2a[24];       // m = 48,49
      const v2f htb = sH2b[24];
      pkfma(ai0, wi[24], hta); pkfma(ai1, wi[24], htb);
      pkfma(af0, wf[24], hta); pkfma(af1, wf[24], htb);
      pkfma(ag0, wg[24], hta); pkfma(ag1, wg[24], htb);
      pkfma(ao0, wo[24], hta); pkfma(ao1, wo[24], htb); }

    const float gi0 = sigm(ai0.x + ai0.y), gi1 = sigm(ai1.x + ai1.y);
    const float gf0 = sigm(af0.x + af0.y), gf1 = sigm(af1.x + af1.y);
    const float gg0 = tanh_f(ag0.x + ag0.y), gg1 = tanh_f(ag1.x + ag1.y);
    const float go0 = sigm(ao0.x + ao0.y), go1 = sigm(ao1.x + ao1.y);
    c0 = fmaf(gf0, c0, gi0 * gg0);
    c1 = fmaf(gf1, c1, gi1 * gg1);
    h0 = act ? go0 * tanh_f(c0) : 0.f;
    h1 = act ? go1 * tanh_f(c1) : 0.f;

    // out[t] per row: dead-end dataflow (nothing downstream reads it), its
    // latency hides under the next step's matvec.
    float p0 = h0 * wout, p1 = h1 * wout;
    p0 += __shfl_xor(p0, 1);  p1 += __shfl_xor(p1, 1);
    p0 += __shfl_xor(p0, 2);  p1 += __shfl_xor(p1, 2);
    p0 += __shfl_xor(p0, 4);  p1 += __shfl_xor(p1, 4);
    p0 += __shfl_xor(p0, 8);  p1 += __shfl_xor(p1, 8);
    p0 += __shfl_xor(p0, 16); p1 += __shfl_xor(p1, 16);
    p0 += __shfl_xor(p0, 32); p1 += __shfl_xor(p1, 32);
    if (lane == 0) { orow0[t] = p0 + bout; orow1[t] = p1 + bout; }
  }
}

extern "C" void kernel_launch(void* const* d_in, const int* in_sizes, int n_in,
                              void* d_out, int out_size, void* d_ws, size_t ws_size,
                              hipStream_t stream) {
  const float* x     = (const float*)d_in[0];
  const float* W_ih  = (const float*)d_in[1];
  const float* W_hh  = (const float*)d_in[2];
  const float* b_ih  = (const float*)d_in[3];
  const float* b_hh  = (const float*)d_in[4];
  const float* W_out = (const float*)d_in[5];
  const float* b_out = (const float*)d_in[6];
  float* out = (float*)d_out;

  lstm_seq_kernel<<<BATCH / RPB, 256, 0, stream>>>(
      x, W_ih, W_hh, b_ih, b_hh, W_out, b_out, out);
}